// Round 5
// baseline (1536.170 us; speedup 1.0000x reference)
//
#include <hip/hip_runtime.h>

// LIF scan: B=16, S=256, H=128, N=64. T = S*H = 32768 sequential steps per
// (b,n) chain; 1024 chains. Bit-exactness with the numpy fp32 sequential
// reference required -> the add chain cannot be reassociated. Chain form
// (proven bit-exact R1/R3/R4, absmax=0):
//     s' = prev ? x : fl(s + x);  prev' = s' > th
//
// R4 post-mortem (863 us, 63 cyc/step): per-step ds_write shares lgkmcnt with
// the scalarized x s_loads -> conservative lgkmcnt(0) drains; plus 256
// barriers each requiring the flush wave's vmcnt(0) store drain. VALU was
// only ~7.5% of active-CU cycles. Fix: decouple entirely.
//
// R5 architecture (checkpoint/replay):
//   Pass 1: pure sequential chains, 16 blocks x 64 lanes. Loop body is ONLY
//     add/cndmask/cmp (8-cyc dep chain). Per 128-step row, store the entering
//     (s, prev-ballot) checkpoint (256 B + 8 B, coalesced) into d_ws. ~1 MB.
//   Pass 2: 4096 single-wave blocks, one (b, s-row) each: replay 128 steps
//     from the checkpoint (bit-identical), stage spike values in LDS, flush
//     outs+spikes as perfectly-coalesced 1 KB wave stores. Dense -> no fill
//     kernel. HBM-write-bound (~268 MB).

namespace {
constexpr int kB = 16;
constexpr int kS = 256;
constexpr int kH = 128;
constexpr int kN = 64;
constexpr int kT = kS * kH;                 // 32768
constexpr long kPerB = (long)kS * kN * kH;  // 2,097,152 per batch per tensor
constexpr size_t kWsS = (size_t)kB * kS * kN * sizeof(float);           // 1 MB
constexpr size_t kWsM = (size_t)kB * kS * sizeof(unsigned long long);   // 32 KB
}

typedef float v4f __attribute__((ext_vector_type(4)));

// ---------------------------------------------------------------------------
// Pass 1: the sequential chains, minimal loop. block = batch, lane = neuron.
// x double-buffered in registers (compiler scalarizes the uniform loads ->
// SGPRs, proven in R3: VGPR=8/SGPR=112). No LDS, no barriers, no per-step
// stores -> nothing couples with the dep chain.
// ---------------------------------------------------------------------------
__global__ __launch_bounds__(64) void lif_pass1_kernel(
    const float* __restrict__ x, const float* __restrict__ thresh,
    const float* __restrict__ acc0, float* __restrict__ ckpt_s,
    unsigned long long* __restrict__ ckpt_m) {
  const int b = blockIdx.x;
  const int lane = threadIdx.x;
  const float th = thresh[lane];
  const v4f* __restrict__ xb4 = (const v4f*)(x + (long)b * kT);

  float s = acc0[b * kN + lane];
  bool prev = false;

  v4f bufA[16], bufB[16];
#pragma unroll
  for (int i = 0; i < 16; ++i) bufA[i] = xb4[i];
#pragma unroll
  for (int i = 0; i < 16; ++i) bufB[i] = xb4[16 + i];

  float* __restrict__ cs = ckpt_s + (long)b * kS * kN + lane;
  unsigned long long* __restrict__ cm = ckpt_m + (long)b * kS;

  for (int row = 0; row < kS; ++row) {
    // Checkpoint the state ENTERING this row: one coalesced 256 B store +
    // one 8 B ballot store. vmcnt-only -> no lgkm coupling with x s_loads.
    cs[(long)row * kN] = s;
    const unsigned long long m = __ballot(prev);
    if (lane == 0) cm[row] = m;

    const v4f* __restrict__ nxt = xb4 + (row + 1) * 32;
#pragma unroll
    for (int k = 0; k < 64; ++k) {
      const float xt = bufA[k >> 2][k & 3];
      const float u = s + xt;   // dep-chain op 1
      s = prev ? xt : u;        // dep-chain op 2
      prev = s > th;            // off-chain
    }
    if (row + 1 < kS) {
#pragma unroll
      for (int i = 0; i < 16; ++i) bufA[i] = nxt[i];
    }
#pragma unroll
    for (int k = 0; k < 64; ++k) {
      const float xt = bufB[k >> 2][k & 3];
      const float u = s + xt;
      s = prev ? xt : u;
      prev = s > th;
    }
    if (row + 1 < kS) {
#pragma unroll
      for (int i = 0; i < 16; ++i) bufB[i] = nxt[16 + i];
    }
  }
}

// ---------------------------------------------------------------------------
// Pass 2: replay + dense coalesced write. One wave per (b, s-row); lane = n
// during replay. Replays the exact chain code -> bit-identical s sequence.
// Stage ov = spike ? s : 0 in LDS [h][n] (+1 pad: writes are (h+lane)%32,
// 2-way = free). Flush remaps lane -> (n = 2i + lane/32, h0 = 4*(lane%32)):
// each wave store instruction covers a contiguous 1 KB. spike flag = ov > 0
// (spiking requires s > th >= 0, so ov > 0 iff spike).
// ---------------------------------------------------------------------------
__global__ __launch_bounds__(64) void lif_pass2_kernel(
    const float* __restrict__ x, const float* __restrict__ thresh,
    const float* __restrict__ ckpt_s,
    const unsigned long long* __restrict__ ckpt_m, float* __restrict__ out) {
  const int wid = blockIdx.x;
  const int b = wid >> 8;
  const int srow = wid & 255;
  const int lane = threadIdx.x;

  __shared__ float ov[kH][kN + 1];

  const float th = thresh[lane];
  float s = ckpt_s[((long)b * kS + srow) * kN + lane];
  bool prev = (ckpt_m[b * kS + srow] >> lane) & 1ULL;
  const float* __restrict__ xr = x + (long)b * kT + srow * kH;

#pragma unroll
  for (int h = 0; h < kH; ++h) {
    const float xt = xr[h];     // wave-uniform
    const float u = s + xt;
    s = prev ? xt : u;          // bit-identical replay
    prev = s > th;
    ov[h][lane] = prev ? s : 0.0f;  // ds_write, imm offset
  }
  __syncthreads();  // single wave: cheap lgkm drain + barrier

  float* __restrict__ obase = out + (long)b * kPerB + (long)srow * (kN * kH);
  float* __restrict__ sbase = obase + (long)kB * kPerB;
  const int h0 = (lane & 31) * 4;
  const int nhalf = lane >> 5;
#pragma unroll
  for (int i = 0; i < 32; ++i) {
    const int n = i * 2 + nhalf;
    v4f o, sp;
#pragma unroll
    for (int j = 0; j < 4; ++j) {
      const float v = ov[h0 + j][n];
      o[j] = v;
      sp[j] = v > 0.0f ? 1.0f : 0.0f;
    }
    __builtin_nontemporal_store(o, (v4f*)(obase + n * kH + h0));   // 1 KB/wave
    __builtin_nontemporal_store(sp, (v4f*)(sbase + n * kH + h0));  // 1 KB/wave
  }
}

// ---------------------------------------------------------------------------
// Fallback (ws too small): R4's passing fused kernel.
// ---------------------------------------------------------------------------
__global__ __launch_bounds__(128) void lif_fused_kernel(
    const float* __restrict__ x, const float* __restrict__ thresh,
    const float* __restrict__ acc0, float* __restrict__ out) {
  const int bid = blockIdx.x;
  const int b = bid >> 2;
  const int ng = bid & 3;
  const int tid = threadIdx.x;
  const int wave = tid >> 6;
  const int lane = tid & 63;
  __shared__ float buf[2][kH][64];
  const float* __restrict__ xb = x + (long)b * kT;
  float* __restrict__ outs_g = out + (long)b * kPerB + (long)(ng * 16) * kH;
  float* __restrict__ spks_g = outs_g + (long)kB * kPerB;
  if (wave == 0) {
    const int n = lane & 15;
    const float th = thresh[ng * 16 + n];
    float s = acc0[b * kN + ng * 16 + n];
    bool prev = false;
    for (int r = 0; r < kS + 1; ++r) {
      if (r < kS) {
        float* __restrict__ bk = &buf[r & 1][0][lane];
        const float* __restrict__ xr = xb + r * kH;
#pragma unroll
        for (int k = 0; k < kH; ++k) {
          const float xt = xr[k];
          const float u = s + xt;
          s = prev ? xt : u;
          prev = s > th;
          bk[k * 64] = s;
        }
      }
      __syncthreads();
    }
  } else {
    const int n = lane >> 2;
    const int hg = lane & 3;
    const float th = thresh[ng * 16 + n];
    for (int r = 0; r < kS + 1; ++r) {
      if (r > 0) {
        const int rr = r - 1;
        const float(*bk)[64] = buf[rr & 1];
        float* __restrict__ orow = outs_g + (long)rr * (kN * kH) + n * kH;
        float* __restrict__ srow = spks_g + (long)rr * (kN * kH) + n * kH;
#pragma unroll
        for (int i = 0; i < 8; ++i) {
          const int h0 = hg * 4 + i * 16;
          v4f ovv, sv;
#pragma unroll
          for (int j = 0; j < 4; ++j) {
            const float v = bk[h0 + j][n];
            const bool sp = v > th;
            ovv[j] = sp ? v : 0.0f;
            sv[j] = sp ? 1.0f : 0.0f;
          }
          *(v4f*)(orow + h0) = ovv;
          *(v4f*)(srow + h0) = sv;
        }
      }
      __syncthreads();
    }
  }
}

// ---------------------------------------------------------------------------
extern "C" void kernel_launch(void* const* d_in, const int* in_sizes, int n_in,
                              void* d_out, int out_size, void* d_ws, size_t ws_size,
                              hipStream_t stream) {
  const float* inputs = (const float*)d_in[0];    // [B,S,H] fp32
  const float* threshes = (const float*)d_in[1];  // [N] fp32
  const float* acc0 = (const float*)d_in[2];      // [B,N] fp32
  float* out = (float*)d_out;

  if (ws_size >= kWsS + kWsM) {
    float* ckpt_s = (float*)d_ws;
    unsigned long long* ckpt_m = (unsigned long long*)((char*)d_ws + kWsS);
    // Pass 1: 16 sequential chain-waves -> 1 MB checkpoints (per-row state).
    lif_pass1_kernel<<<kB, kN, 0, stream>>>(inputs, threshes, acc0, ckpt_s,
                                            ckpt_m);
    // Pass 2: 4096 independent row-replays -> dense coalesced output.
    lif_pass2_kernel<<<kB * kS, kN, 0, stream>>>(inputs, threshes, ckpt_s,
                                                 ckpt_m, out);
  } else {
    lif_fused_kernel<<<kB * 4, 128, 0, stream>>>(inputs, threshes, acc0, out);
  }
}

// Round 6
// 743.194 us; speedup vs baseline: 2.0670x; 2.0670x over previous
//
#include <hip/hip_runtime.h>

// LIF scan: B=16, S=256, H=128, N=64. T = S*H = 32768 sequential steps per
// (b,n) chain; 1024 chains. Bit-exactness with the numpy fp32 sequential
// reference required -> the add chain cannot be reassociated. Chain form
// (proven bit-exact R1/R3/R4/R5, absmax=0):
//     s' = prev ? x : fl(s + x);  prev' = s' > th
//
// R5 post-mortem (pass1 = 1271 us = 93 cyc/step, VGPR=8/SGPR=112): the
// compiler scalarizes the wave-uniform x loads into SMEM s_loads. SMEM
// returns are UNORDERED -> every use needs lgkmcnt(0), draining the whole
// prefetch queue: ~300 cyc stall per small chunk. The fix is to force the
// VECTOR memory path (vmcnt is in-order -> fine-grained waits, deep
// pipelining): an opaque VGPR zero (inline-asm v_mov) in the address defeats
// uniform-scalarization; x buffers then live in VGPRs (128 regs, budget 512)
// and global_load_dwordx4 broadcast-loads (all lanes same address = 1 line)
// stay >=512 cyc in flight ahead of use.
//
// Architecture (checkpoint/replay):
//   Pass 1: pure chains, 16 blocks x 64 lanes; per 128-step row store the
//     entering (s, ballot) checkpoint (256 B + 8 B) into d_ws. 8-cyc dep
//     chain floor -> ~110 us.
//   Pass 2: 4096 single-wave blocks, one (b,row) each: bit-identical replay
//     from checkpoint, stage ov in LDS, flush outs+spikes as 1 KB coalesced
//     wave stores. Dense writes -> no fill pass. HBM-write-bound (~268 MB).

namespace {
constexpr int kB = 16;
constexpr int kS = 256;
constexpr int kH = 128;
constexpr int kN = 64;
constexpr int kT = kS * kH;                 // 32768
constexpr long kPerB = (long)kS * kN * kH;  // 2,097,152 per batch per tensor
constexpr size_t kWsS = (size_t)kB * kS * kN * sizeof(float);          // 1 MB
constexpr size_t kWsM = (size_t)kB * kS * sizeof(unsigned long long);  // 32 KB
}

typedef float v4f __attribute__((ext_vector_type(4)));

// Opaque VGPR zero: the compiler cannot prove it uniform, so addresses built
// from it stay divergent -> global_load (vmcnt) instead of s_load (lgkmcnt).
__device__ __forceinline__ int opaque_vgpr_zero() {
  int z;
  asm volatile("v_mov_b32 %0, 0" : "=v"(z));
  return z;
}

// ---------------------------------------------------------------------------
// Pass 1: the sequential chains, minimal loop. block = batch, lane = neuron.
// x double-buffered in VGPRs (2 x 16 dwordx4 broadcast loads); checkpoint
// stores are vmcnt-only and never waited on.
// ---------------------------------------------------------------------------
__global__ __launch_bounds__(64) void lif_pass1_kernel(
    const float* __restrict__ x, const float* __restrict__ thresh,
    const float* __restrict__ acc0, float* __restrict__ ckpt_s,
    unsigned long long* __restrict__ ckpt_m) {
  const int b = blockIdx.x;
  const int lane = threadIdx.x;
  const float th = thresh[lane];

  const v4f* __restrict__ xb4 =
      (const v4f*)(x + (long)b * kT) + opaque_vgpr_zero();

  float s = acc0[b * kN + lane];
  bool prev = false;

  v4f bufA[16], bufB[16];
#pragma unroll
  for (int i = 0; i < 16; ++i) bufA[i] = xb4[i];
#pragma unroll
  for (int i = 0; i < 16; ++i) bufB[i] = xb4[16 + i];

  float* __restrict__ cs = ckpt_s + (long)b * kS * kN + lane;
  unsigned long long* __restrict__ cm = ckpt_m + (long)b * kS;

  for (int row = 0; row < kS; ++row) {
    // Checkpoint the state ENTERING this row (coalesced 256 B + 8 B).
    cs[(long)row * kN] = s;
    const unsigned long long m = __ballot(prev);
    if (lane == 0) cm[row] = m;

    const v4f* __restrict__ nxt = xb4 + (row + 1) * 32;

    // steps 0..63 from bufA (bufB's loads already >=1 row in flight)
#pragma unroll
    for (int k = 0; k < 64; ++k) {
      const float xt = bufA[k >> 2][k & 3];  // VGPR operand, zero latency
      const float u = s + xt;                // dep-chain op 1 (4 cyc)
      s = prev ? xt : u;                     // dep-chain op 2 (4 cyc)
      prev = s > th;                         // off-chain
    }
    if (row + 1 < kS) {
#pragma unroll
      for (int i = 0; i < 16; ++i) bufA[i] = nxt[i];  // 512-cyc cover
    }

    // steps 64..127 from bufB
#pragma unroll
    for (int k = 0; k < 64; ++k) {
      const float xt = bufB[k >> 2][k & 3];
      const float u = s + xt;
      s = prev ? xt : u;
      prev = s > th;
    }
    if (row + 1 < kS) {
#pragma unroll
      for (int i = 0; i < 16; ++i) bufB[i] = nxt[16 + i];
    }
  }
}

// ---------------------------------------------------------------------------
// Pass 2: replay + dense coalesced write. One wave per (b,row); lane = n.
// Replays the exact chain ops from the checkpoint -> bit-identical s
// sequence. x row preloaded into 32 VGPR quads (vmcnt-pipelined broadcast
// loads). ov staged in LDS [h][n] (+1 pad); flush remaps lanes so each wave
// store instruction covers a contiguous 1 KB. spike flag = ov > 0 (spiking
// requires s > th >= 0) — proven bit-exact in R5.
// ---------------------------------------------------------------------------
__global__ __launch_bounds__(64) void lif_pass2_kernel(
    const float* __restrict__ x, const float* __restrict__ thresh,
    const float* __restrict__ ckpt_s,
    const unsigned long long* __restrict__ ckpt_m, float* __restrict__ out) {
  const int wid = blockIdx.x;
  const int b = wid >> 8;
  const int srow = wid & 255;
  const int lane = threadIdx.x;

  __shared__ float ov[kH][kN + 1];

  const v4f* __restrict__ xr4 =
      (const v4f*)(x + (long)b * kT + srow * kH) + opaque_vgpr_zero();

  v4f xb[32];
#pragma unroll
  for (int i = 0; i < 32; ++i) xb[i] = xr4[i];  // 32 loads in flight

  const float th = thresh[lane];
  float s = ckpt_s[((long)b * kS + srow) * kN + lane];
  bool prev = (ckpt_m[b * kS + srow] >> lane) & 1ULL;

#pragma unroll
  for (int h = 0; h < kH; ++h) {
    const float xt = xb[h >> 2][h & 3];
    const float u = s + xt;
    s = prev ? xt : u;             // bit-identical replay
    prev = s > th;
    ov[h][lane] = prev ? s : 0.0f; // ds_write, imm offset
  }
  __syncthreads();

  float* __restrict__ obase = out + (long)b * kPerB + (long)srow * (kN * kH);
  float* __restrict__ sbase = obase + (long)kB * kPerB;
  const int h0 = (lane & 31) * 4;
  const int nhalf = lane >> 5;
#pragma unroll
  for (int i = 0; i < 32; ++i) {
    const int n = i * 2 + nhalf;
    v4f o, sp;
#pragma unroll
    for (int j = 0; j < 4; ++j) {
      const float v = ov[h0 + j][n];
      o[j] = v;
      sp[j] = v > 0.0f ? 1.0f : 0.0f;
    }
    __builtin_nontemporal_store(o, (v4f*)(obase + n * kH + h0));   // 1 KB/wave
    __builtin_nontemporal_store(sp, (v4f*)(sbase + n * kH + h0));  // 1 KB/wave
  }
}

// ---------------------------------------------------------------------------
// Fallback (ws too small): R4's passing fused kernel (1060 us).
// ---------------------------------------------------------------------------
__global__ __launch_bounds__(128) void lif_fused_kernel(
    const float* __restrict__ x, const float* __restrict__ thresh,
    const float* __restrict__ acc0, float* __restrict__ out) {
  const int bid = blockIdx.x;
  const int b = bid >> 2;
  const int ng = bid & 3;
  const int tid = threadIdx.x;
  const int wave = tid >> 6;
  const int lane = tid & 63;
  __shared__ float buf[2][kH][64];
  const float* __restrict__ xb = x + (long)b * kT;
  float* __restrict__ outs_g = out + (long)b * kPerB + (long)(ng * 16) * kH;
  float* __restrict__ spks_g = outs_g + (long)kB * kPerB;
  if (wave == 0) {
    const int n = lane & 15;
    const float th = thresh[ng * 16 + n];
    float s = acc0[b * kN + ng * 16 + n];
    bool prev = false;
    for (int r = 0; r < kS + 1; ++r) {
      if (r < kS) {
        float* __restrict__ bk = &buf[r & 1][0][lane];
        const float* __restrict__ xr = xb + r * kH;
#pragma unroll
        for (int k = 0; k < kH; ++k) {
          const float xt = xr[k];
          const float u = s + xt;
          s = prev ? xt : u;
          prev = s > th;
          bk[k * 64] = s;
        }
      }
      __syncthreads();
    }
  } else {
    const int n = lane >> 2;
    const int hg = lane & 3;
    const float th = thresh[ng * 16 + n];
    for (int r = 0; r < kS + 1; ++r) {
      if (r > 0) {
        const int rr = r - 1;
        const float(*bk)[64] = buf[rr & 1];
        float* __restrict__ orow = outs_g + (long)rr * (kN * kH) + n * kH;
        float* __restrict__ srow = spks_g + (long)rr * (kN * kH) + n * kH;
#pragma unroll
        for (int i = 0; i < 8; ++i) {
          const int hh = hg * 4 + i * 16;
          v4f ovv, sv;
#pragma unroll
          for (int j = 0; j < 4; ++j) {
            const float v = bk[hh + j][n];
            const bool sp = v > th;
            ovv[j] = sp ? v : 0.0f;
            sv[j] = sp ? 1.0f : 0.0f;
          }
          *(v4f*)(orow + hh) = ovv;
          *(v4f*)(srow + hh) = sv;
        }
      }
      __syncthreads();
    }
  }
}

// ---------------------------------------------------------------------------
extern "C" void kernel_launch(void* const* d_in, const int* in_sizes, int n_in,
                              void* d_out, int out_size, void* d_ws, size_t ws_size,
                              hipStream_t stream) {
  const float* inputs = (const float*)d_in[0];    // [B,S,H] fp32
  const float* threshes = (const float*)d_in[1];  // [N] fp32
  const float* acc0 = (const float*)d_in[2];      // [B,N] fp32
  float* out = (float*)d_out;

  if (ws_size >= kWsS + kWsM) {
    float* ckpt_s = (float*)d_ws;
    unsigned long long* ckpt_m = (unsigned long long*)((char*)d_ws + kWsS);
    lif_pass1_kernel<<<kB, kN, 0, stream>>>(inputs, threshes, acc0, ckpt_s,
                                            ckpt_m);
    lif_pass2_kernel<<<kB * kS, kN, 0, stream>>>(inputs, threshes, ckpt_s,
                                                 ckpt_m, out);
  } else {
    lif_fused_kernel<<<kB * 4, 128, 0, stream>>>(inputs, threshes, acc0, out);
  }
}

// Round 7
// 599.284 us; speedup vs baseline: 2.5633x; 1.2401x over previous
//
#include <hip/hip_runtime.h>

// LIF scan: B=16, S=256, H=128, N=64. T = S*H = 32768 sequential steps per
// (b,n) chain; 1024 chains. Bit-exactness with the numpy fp32 sequential
// reference required -> the add chain cannot be reassociated. Chain form
// (proven bit-exact R1..R6, absmax=0):
//     s' = prev ? x : fl(s + x);  prev' = s' > th
//
// R6 post-mortem: opaque-VGPR address trick moved x to the vector path
// (VGPR 8->136) and pass1 1271->476 us = 34.8 cyc/step. Still ~3-4x the
// 8-10 cyc dep-chain floor; VALU issue is only ~4 cyc/step -> residual is
// vmcnt stalls at half-row boundaries: the R6 "double buffer" only gives a
// 64-step lookahead (~640 cyc at target pace) vs ~900 cyc HBM latency
// (FETCH 1 MB -> half the x stream misses L2).
//
// R7: 4-stage static-register pipeline in pass1: buffers A..D (16 x float4
// each, 256 VGPRs, launch_bounds(64,1)); load chunk c+4 right after
// consuming chunk c -> 192-step (~1900 cyc) lookahead. All chunk indices
// statically unrolled so buffers never touch scratch. Pass2 byte-identical
// to R6 to isolate the change.

namespace {
constexpr int kB = 16;
constexpr int kS = 256;
constexpr int kH = 128;
constexpr int kN = 64;
constexpr int kT = kS * kH;                 // 32768
constexpr long kPerB = (long)kS * kN * kH;  // 2,097,152 per batch per tensor
constexpr size_t kWsS = (size_t)kB * kS * kN * sizeof(float);          // 1 MB
constexpr size_t kWsM = (size_t)kB * kS * sizeof(unsigned long long);  // 32 KB
}

typedef float v4f __attribute__((ext_vector_type(4)));

// Opaque VGPR zero: defeats uniform-scalarization so x loads use the vector
// path (vmcnt, in-order, pipelineable) instead of SMEM s_loads (lgkmcnt,
// unordered -> full drains). Proven effective in R6 (VGPR 8->136).
__device__ __forceinline__ int opaque_vgpr_zero() {
  int z;
  asm volatile("v_mov_b32 %0, 0" : "=v"(z));
  return z;
}

__device__ __forceinline__ void load16(v4f (&buf)[16], const v4f* __restrict__ p) {
#pragma unroll
  for (int i = 0; i < 16; ++i) buf[i] = p[i];
}

__device__ __forceinline__ void consume64(const v4f (&buf)[16], float& s,
                                          bool& prev, float th) {
#pragma unroll
  for (int k = 0; k < 64; ++k) {
    const float xt = buf[k >> 2][k & 3];  // static VGPR
    const float u = s + xt;               // dep-chain op 1
    s = prev ? xt : u;                    // dep-chain op 2 (cndmask)
    prev = s > th;                        // off-chain cmp
  }
}

// ---------------------------------------------------------------------------
// Pass 1: the sequential chains. block = batch, lane = neuron. 512 chunks of
// 64 steps; 4-stage register pipeline (lookahead = 192 steps ~ 1900 cyc).
// Checkpoints (entering-state s + prev ballot) at every even chunk (= row).
// ---------------------------------------------------------------------------
__global__ __launch_bounds__(64, 1) void lif_pass1_kernel(
    const float* __restrict__ x, const float* __restrict__ thresh,
    const float* __restrict__ acc0, float* __restrict__ ckpt_s,
    unsigned long long* __restrict__ ckpt_m) {
  const int b = blockIdx.x;
  const int lane = threadIdx.x;
  const float th = thresh[lane];

  const v4f* __restrict__ xb4 =
      (const v4f*)(x + (long)b * kT) + opaque_vgpr_zero();

  float s = acc0[b * kN + lane];
  bool prev = false;

  v4f A[16], Bv[16], C[16], D[16];
  load16(A, xb4 + 0 * 16);
  load16(Bv, xb4 + 1 * 16);
  load16(C, xb4 + 2 * 16);
  load16(D, xb4 + 3 * 16);

  float* __restrict__ cs = ckpt_s + (long)b * kS * kN + lane;
  unsigned long long* __restrict__ cm = ckpt_m + (long)b * kS;

  for (int g = 0; g < 128; ++g) {
    const int c0 = 4 * g;
    // clamped prefetch pointers (tail reloads chunk 511; in-bounds, unused)
    const v4f* pA = xb4 + 16 * (c0 + 4 < 512 ? c0 + 4 : 511);
    const v4f* pB = xb4 + 16 * (c0 + 5 < 512 ? c0 + 5 : 511);
    const v4f* pC = xb4 + 16 * (c0 + 6 < 512 ? c0 + 6 : 511);
    const v4f* pD = xb4 + 16 * (c0 + 7 < 512 ? c0 + 7 : 511);

    // ---- row 2g: checkpoint entering state ----
    cs[(long)(2 * g) * kN] = s;
    {
      const unsigned long long m = __ballot(prev);
      if (lane == 0) cm[2 * g] = m;
    }
    consume64(A, s, prev, th);   // chunk c0
    load16(A, pA);               // prefetch c0+4 (192-step lookahead)
    consume64(Bv, s, prev, th);  // chunk c0+1
    load16(Bv, pB);

    // ---- row 2g+1: checkpoint entering state ----
    cs[(long)(2 * g + 1) * kN] = s;
    {
      const unsigned long long m = __ballot(prev);
      if (lane == 0) cm[2 * g + 1] = m;
    }
    consume64(C, s, prev, th);   // chunk c0+2
    load16(C, pC);
    consume64(D, s, prev, th);   // chunk c0+3
    load16(D, pD);
  }
}

// ---------------------------------------------------------------------------
// Pass 2: replay + dense coalesced write (byte-identical to R6). One wave
// per (b,row); lane = n. Bit-identical replay from checkpoint; ov staged in
// LDS; flush as contiguous 1 KB wave stores. spike = ov > 0.
// ---------------------------------------------------------------------------
__global__ __launch_bounds__(64) void lif_pass2_kernel(
    const float* __restrict__ x, const float* __restrict__ thresh,
    const float* __restrict__ ckpt_s,
    const unsigned long long* __restrict__ ckpt_m, float* __restrict__ out) {
  const int wid = blockIdx.x;
  const int b = wid >> 8;
  const int srow = wid & 255;
  const int lane = threadIdx.x;

  __shared__ float ov[kH][kN + 1];

  const v4f* __restrict__ xr4 =
      (const v4f*)(x + (long)b * kT + srow * kH) + opaque_vgpr_zero();

  v4f xb[32];
#pragma unroll
  for (int i = 0; i < 32; ++i) xb[i] = xr4[i];  // 32 loads in flight

  const float th = thresh[lane];
  float s = ckpt_s[((long)b * kS + srow) * kN + lane];
  bool prev = (ckpt_m[b * kS + srow] >> lane) & 1ULL;

#pragma unroll
  for (int h = 0; h < kH; ++h) {
    const float xt = xb[h >> 2][h & 3];
    const float u = s + xt;
    s = prev ? xt : u;              // bit-identical replay
    prev = s > th;
    ov[h][lane] = prev ? s : 0.0f;  // ds_write, imm offset
  }
  __syncthreads();

  float* __restrict__ obase = out + (long)b * kPerB + (long)srow * (kN * kH);
  float* __restrict__ sbase = obase + (long)kB * kPerB;
  const int h0 = (lane & 31) * 4;
  const int nhalf = lane >> 5;
#pragma unroll
  for (int i = 0; i < 32; ++i) {
    const int n = i * 2 + nhalf;
    v4f o, sp;
#pragma unroll
    for (int j = 0; j < 4; ++j) {
      const float v = ov[h0 + j][n];
      o[j] = v;
      sp[j] = v > 0.0f ? 1.0f : 0.0f;
    }
    __builtin_nontemporal_store(o, (v4f*)(obase + n * kH + h0));   // 1 KB/wave
    __builtin_nontemporal_store(sp, (v4f*)(sbase + n * kH + h0));  // 1 KB/wave
  }
}

// ---------------------------------------------------------------------------
// Fallback (ws too small): R4's passing fused kernel.
// ---------------------------------------------------------------------------
__global__ __launch_bounds__(128) void lif_fused_kernel(
    const float* __restrict__ x, const float* __restrict__ thresh,
    const float* __restrict__ acc0, float* __restrict__ out) {
  const int bid = blockIdx.x;
  const int b = bid >> 2;
  const int ng = bid & 3;
  const int tid = threadIdx.x;
  const int wave = tid >> 6;
  const int lane = tid & 63;
  __shared__ float buf[2][kH][64];
  const float* __restrict__ xb = x + (long)b * kT;
  float* __restrict__ outs_g = out + (long)b * kPerB + (long)(ng * 16) * kH;
  float* __restrict__ spks_g = outs_g + (long)kB * kPerB;
  if (wave == 0) {
    const int n = lane & 15;
    const float th = thresh[ng * 16 + n];
    float s = acc0[b * kN + ng * 16 + n];
    bool prev = false;
    for (int r = 0; r < kS + 1; ++r) {
      if (r < kS) {
        float* __restrict__ bk = &buf[r & 1][0][lane];
        const float* __restrict__ xr = xb + r * kH;
#pragma unroll
        for (int k = 0; k < kH; ++k) {
          const float xt = xr[k];
          const float u = s + xt;
          s = prev ? xt : u;
          prev = s > th;
          bk[k * 64] = s;
        }
      }
      __syncthreads();
    }
  } else {
    const int n = lane >> 2;
    const int hg = lane & 3;
    const float th = thresh[ng * 16 + n];
    for (int r = 0; r < kS + 1; ++r) {
      if (r > 0) {
        const int rr = r - 1;
        const float(*bk)[64] = buf[rr & 1];
        float* __restrict__ orow = outs_g + (long)rr * (kN * kH) + n * kH;
        float* __restrict__ srow = spks_g + (long)rr * (kN * kH) + n * kH;
#pragma unroll
        for (int i = 0; i < 8; ++i) {
          const int hh = hg * 4 + i * 16;
          v4f ovv, sv;
#pragma unroll
          for (int j = 0; j < 4; ++j) {
            const float v = bk[hh + j][n];
            const bool sp = v > th;
            ovv[j] = sp ? v : 0.0f;
            sv[j] = sp ? 1.0f : 0.0f;
          }
          *(v4f*)(orow + hh) = ovv;
          *(v4f*)(srow + hh) = sv;
        }
      }
      __syncthreads();
    }
  }
}

// ---------------------------------------------------------------------------
extern "C" void kernel_launch(void* const* d_in, const int* in_sizes, int n_in,
                              void* d_out, int out_size, void* d_ws, size_t ws_size,
                              hipStream_t stream) {
  const float* inputs = (const float*)d_in[0];    // [B,S,H] fp32
  const float* threshes = (const float*)d_in[1];  // [N] fp32
  const float* acc0 = (const float*)d_in[2];      // [B,N] fp32
  float* out = (float*)d_out;

  if (ws_size >= kWsS + kWsM) {
    float* ckpt_s = (float*)d_ws;
    unsigned long long* ckpt_m = (unsigned long long*)((char*)d_ws + kWsS);
    lif_pass1_kernel<<<kB, kN, 0, stream>>>(inputs, threshes, acc0, ckpt_s,
                                            ckpt_m);
    lif_pass2_kernel<<<kB * kS, kN, 0, stream>>>(inputs, threshes, ckpt_s,
                                                 ckpt_m, out);
  } else {
    lif_fused_kernel<<<kB * 4, 128, 0, stream>>>(inputs, threshes, acc0, out);
  }
}